// Round 14
// baseline (164.911 us; speedup 1.0000x reference)
//
#include <hip/hip_runtime.h>
#include <hip/hip_bf16.h>

// SO3Conv restructured:
//   PT_l[(yo,v)][(x,u)] = psi_l scaled, bf16   (psi = D.w/sqrt(512))
//   A_l[(b,i)][(x,u)]   = permuted x, bf16
//   Y_l[(b,i)][(yo,v)]  = A_l . PT_l^T  via mfma_f32_16x16x32_bf16
// l=0..5, d=2l+1, off_l = {0,1,10,35,84,165}.
// main_gemm8: 256x256 tiles, BK=32, 8 waves (2x4), 4-phase fine interleave
// per 2 K-tiles, 8 LDS chunks (8KB) double-parity, counted vmcnt(2),
// raw barriers, setprio MFMA clusters. 322 blocks x 512 thr.

#define NT 256
#define NT8 512
typedef __bf16 bf16x8 __attribute__((ext_vector_type(8)));
typedef float f32x4 __attribute__((ext_vector_type(4)));
typedef unsigned int u32;

__device__ __forceinline__ void gload_lds16(const void* g, void* l) {
  __builtin_amdgcn_global_load_lds(
      (const __attribute__((address_space(1))) u32*)g,
      (__attribute__((address_space(3))) u32*)l, 16, 0, 0);
}

__device__ __forceinline__ void decode_s(int s, int& off, int& d) {
  if (s >= 165)      { off = 165; d = 11; }
  else if (s >= 84)  { off = 84;  d = 9; }
  else if (s >= 35)  { off = 35;  d = 7; }
  else if (s >= 10)  { off = 10;  d = 5; }
  else if (s >= 1)   { off = 1;   d = 3; }
  else               { off = 0;   d = 1; }
}

// ---------------------------------------------------------------------------
// Kernel 0: prep_all (7936 blocks): wb=bf16(w); DT=bf16(D^T) padded; build_A.
// ---------------------------------------------------------------------------
template<int D, int OFF>
__device__ __forceinline__ void build_one(const float* __restrict__ X,
                                          __hip_bfloat16* __restrict__ A,
                                          int b, __hip_bfloat16* sm) {
  const float* src = X + (size_t)b * (128 * 286) + OFF;
  for (int e = threadIdx.x; e < 128 * D * D; e += NT) {
    const int x = e / (D * D), r = e - x * (D * D);
    sm[e] = __float2bfloat16(src[x * 286 + r]);
  }
  __syncthreads();
  __hip_bfloat16* dst = A + (size_t)65536 * OFF + (size_t)b * (D * 128 * D);
  for (int o = threadIdx.x; o < D * 128 * D; o += NT) {
    const int i = o / (128 * D);
    const int rem = o - i * (128 * D);
    const int x = rem / D, u = rem - x * D;
    dst[o] = sm[x * D * D + u * D + i];
  }
}

__global__ __launch_bounds__(NT)
void prep_all(const float* __restrict__ w, const float* __restrict__ Dm,
              const float* __restrict__ X,
              __hip_bfloat16* __restrict__ wb, __hip_bfloat16* __restrict__ DT,
              __hip_bfloat16* __restrict__ A) {
  __shared__ __hip_bfloat16 sm[128 * 121];
  const int bx = blockIdx.x;
  if (bx < 4096) {
    const int t = bx * NT + threadIdx.x;
    const float4 a = reinterpret_cast<const float4*>(w)[t * 2];
    const float4 b = reinterpret_cast<const float4*>(w)[t * 2 + 1];
    __hip_bfloat16 v[8];
    v[0] = __float2bfloat16(a.x); v[1] = __float2bfloat16(a.y);
    v[2] = __float2bfloat16(a.z); v[3] = __float2bfloat16(a.w);
    v[4] = __float2bfloat16(b.x); v[5] = __float2bfloat16(b.y);
    v[6] = __float2bfloat16(b.z); v[7] = __float2bfloat16(b.w);
    *reinterpret_cast<bf16x8*>(&wb[t * 8]) = *reinterpret_cast<bf16x8*>(v);
  } else if (bx < 4864) {
    const int e = (bx - 4096) * NT + threadIdx.x;  // 196,608 = 384*512
    const int s = e >> 9, g = e & 511;
    DT[e] = (s < 286) ? __float2bfloat16(Dm[g * 286 + s]) : __float2bfloat16(0.0f);
  } else {
    const int b2 = bx - 4864;
    if (b2 < 512)       build_one<11, 165>(X, A, b2, sm);
    else if (b2 < 1024) build_one<9, 84>(X, A, b2 - 512, sm);
    else if (b2 < 1536) build_one<7, 35>(X, A, b2 - 1024, sm);
    else if (b2 < 2048) build_one<5, 10>(X, A, b2 - 1536, sm);
    else if (b2 < 2560) build_one<3, 1>(X, A, b2 - 2048, sm);
    else                build_one<1, 0>(X, A, b2 - 2560, sm);
  }
}

// ---------------------------------------------------------------------------
// psi helpers + kernel (proven R7/R8 structure; unchanged).
// ---------------------------------------------------------------------------
__device__ __forceinline__ void stage_tile(
    const __hip_bfloat16* __restrict__ Ap, const __hip_bfloat16* __restrict__ Bp,
    int LDK, int ktv, int m0, int n0, int tid, int wave,
    __hip_bfloat16* sA, __hip_bfloat16* sB) {
#pragma unroll
  for (int c = 0; c < 4; ++c) {
    const int q = c * 256 + tid;
    const int row = q >> 3, slot = q & 7;
    const int scol = ((slot ^ (row & 7)) << 3);
    gload_lds16(&Ap[(m0 + row) * LDK + ktv + scol], &sA[(c * 256 + wave * 64) << 3]);
    gload_lds16(&Bp[(n0 + row) * LDK + ktv + scol], &sB[(c * 256 + wave * 64) << 3]);
  }
}

__device__ __forceinline__ void load_frags(
    const __hip_bfloat16* sA, const __hip_bfloat16* sB,
    int wr, int wc, int r15, int khi, bf16x8 (&af)[4][2], bf16x8 (&bf)[4][2]) {
#pragma unroll
  for (int m = 0; m < 4; ++m)
#pragma unroll
    for (int kk = 0; kk < 2; ++kk) {
      const int row = wr * 64 + m * 16 + r15;
      const int slot = (kk * 4 + khi) ^ (row & 7);
      af[m][kk] = *reinterpret_cast<const bf16x8*>(&sA[row * 64 + slot * 8]);
    }
#pragma unroll
  for (int n = 0; n < 4; ++n)
#pragma unroll
    for (int kk = 0; kk < 2; ++kk) {
      const int row = wc * 64 + n * 16 + r15;
      const int slot = (kk * 4 + khi) ^ (row & 7);
      bf[n][kk] = *reinterpret_cast<const bf16x8*>(&sB[row * 64 + slot * 8]);
    }
}

__device__ __forceinline__ void do_mfma(
    const bf16x8 (&af)[4][2], const bf16x8 (&bf)[4][2], f32x4 (&acc)[4][4]) {
#pragma unroll
  for (int kk = 0; kk < 2; ++kk)
#pragma unroll
    for (int m = 0; m < 4; ++m)
#pragma unroll
      for (int n = 0; n < 4; ++n)
        acc[m][n] = __builtin_amdgcn_mfma_f32_16x16x32_bf16(
            af[m][kk], bf[n][kk], acc[m][n], 0, 0, 0);
}

__global__ __launch_bounds__(NT)
void psi_mfma(const __hip_bfloat16* __restrict__ wb,
              const __hip_bfloat16* __restrict__ DT,
              __hip_bfloat16* __restrict__ PT) {
  const int m0 = blockIdx.x * 128, n0 = blockIdx.y * 128;

  __shared__ __hip_bfloat16 sA[2][128 * 64];
  __shared__ __hip_bfloat16 sB[2][128 * 64];

  const int tid = threadIdx.x;
  const int lane = tid & 63, wave = tid >> 6;
  const int wr = wave & 1, wc = wave >> 1;
  const int r15 = lane & 15, khi = lane >> 4;

  f32x4 acc[4][4] = {};
  bf16x8 af[4][2], bf[4][2];

  stage_tile(wb, DT, 512, 0, m0, n0, tid, wave, sA[0], sB[0]);
  __syncthreads();
  int cur = 0;
  for (int t = 0; t < 8; ++t) {
    if (t + 1 < 8)
      stage_tile(wb, DT, 512, (t + 1) << 6, m0, n0, tid, wave, sA[cur ^ 1], sB[cur ^ 1]);
    load_frags(sA[cur], sB[cur], wr, wc, r15, khi, af, bf);
    do_mfma(af, bf, acc);
    if (t + 1 < 8) { __syncthreads(); cur ^= 1; }
  }

#pragma unroll
  for (int n = 0; n < 4; ++n) {
    const int s = n0 + wc * 64 + n * 16 + r15;
    if (s >= 286) continue;
    int off, d;
    decode_s(s, off, d);
    const int rel = s - off;
    const int u = rel / d, v = rel - u * d;
    const float scale = 1.0f / (256.0f * sqrtf((float)d));
    __hip_bfloat16* Pl = PT + off * 16384;
    const int Kd = 128 * d;
#pragma unroll
    for (int m = 0; m < 4; ++m)
#pragma unroll
      for (int j = 0; j < 4; ++j) {
        const int row = m0 + wr * 64 + m * 16 + khi * 4 + j;
        const int x = row >> 7, y = row & 127;
        Pl[(y * d + v) * Kd + (x * d + u)] = __float2bfloat16(acc[m][n][j] * scale);
      }
  }
}

// ---------------------------------------------------------------------------
// main_gemm8: 256x256 tile, BK=32, 8 waves (wr 0..1 x wc 0..3), per-wave
// 128x64 (acc[8][4]). LDS: 8 chunks x 8KB = 64KB: [parity][A,B][half].
// 4 phases per iteration (2 K-tiles): ph(par, mh) with counted vmcnt.
// Stage slots: ph1 A[1]<-k+1, ph2 B[0]<-k+2, ph3 A[0]<-k+2, ph4 B[1]<-k+3.
// vmcnt(2) at ph2/ph4 (before barrier); tail iter: vmcnt(0) at ph2, skip rest.
// ---------------------------------------------------------------------------
#define VMC2() asm volatile("s_waitcnt vmcnt(2)" ::: "memory")
#define VMC0() asm volatile("s_waitcnt vmcnt(0)" ::: "memory")
#define BAR()  do { asm volatile("" ::: "memory"); __builtin_amdgcn_s_barrier(); \
                    asm volatile("" ::: "memory"); } while (0)

template<int D, int OFF>
__device__ __forceinline__ void tile8(const __hip_bfloat16* __restrict__ Aall,
                                      const __hip_bfloat16* __restrict__ PTall,
                                      float* __restrict__ out, int sub,
                                      __hip_bfloat16* smem) {
  const int tid = threadIdx.x;
  const int lane = tid & 63, wave = tid >> 6;
  const int wr = wave >> 2, wc = wave & 3;
  const int r15 = lane & 15, khi = lane >> 4;

  constexpr int Kn = 128 * D, NnM = 128 * D;
  constexpr int NBM = 2 * D;
  constexpr int ni = 2 * D;                 // iterations; 4D K-tiles of 32
  const int bm = sub % NBM, bn = sub / NBM;
  const int m0 = bm * 256, n0 = bn * 256;
  const __hip_bfloat16* A  = Aall  + 65536 * OFF;
  const __hip_bfloat16* BT = PTall + 16384 * OFF;

  // staging geometry: 512 threads x 1 load per half-chunk (128 rows x 32 bf16)
  const int srow = tid >> 2, sslot = tid & 3;
  const int scol = ((sslot ^ (srow & 3)) << 3);
  const int garA0 = m0 + srow, garA1 = m0 + 128 + srow;
  int gbr0 = n0 + srow;       if (gbr0 >= NnM) gbr0 = NnM - 1;
  int gbr1 = n0 + 128 + srow; if (gbr1 >= NnM) gbr1 = NnM - 1;
  const int dstoff = wave * 512;            // elems; +lane*16B implicit

  // chunk base (elems): ((par*2 + op)*2 + half) * 4096
  __hip_bfloat16* cA[2] = { smem + (0 * 4 + 0 * 2 + wr) * 4096,
                            smem + (1 * 4 + 0 * 2 + wr) * 4096 };
  __hip_bfloat16* cB[2] = { smem + (0 * 4 + 1 * 2 + (wc >> 1)) * 4096,
                            smem + (1 * 4 + 1 * 2 + (wc >> 1)) * 4096 };

#define STG_A(par, kt) do {                                                   \
    gload_lds16(&A[(size_t)garA0 * Kn + (kt) * 32 + scol],                    \
                smem + ((par) * 4 + 0) * 4096 + dstoff);                      \
    gload_lds16(&A[(size_t)garA1 * Kn + (kt) * 32 + scol],                    \
                smem + ((par) * 4 + 1) * 4096 + dstoff);                      \
  } while (0)
#define STG_B(par, kt) do {                                                   \
    gload_lds16(&BT[(size_t)gbr0 * Kn + (kt) * 32 + scol],                    \
                smem + ((par) * 4 + 2) * 4096 + dstoff);                      \
    gload_lds16(&BT[(size_t)gbr1 * Kn + (kt) * 32 + scol],                    \
                smem + ((par) * 4 + 3) * 4096 + dstoff);                      \
  } while (0)
#define RD_AF(mh, par) { _Pragma("unroll")                                    \
    for (int mm = 0; mm < 4; ++mm) {                                          \
      const int lr = (mh) * 64 + mm * 16 + r15;                               \
      af[mm] = *reinterpret_cast<const bf16x8*>(                              \
          &cA[par][lr * 32 + ((khi ^ (lr & 3)) << 3)]);                       \
    } }
#define RD_BF(par) { _Pragma("unroll")                                        \
    for (int nn = 0; nn < 4; ++nn) {                                          \
      const int lr = (wc & 1) * 64 + nn * 16 + r15;                           \
      bf[nn] = *reinterpret_cast<const bf16x8*>(                              \
          &cB[par][lr * 32 + ((khi ^ (lr & 3)) << 3)]);                       \
    } }
#define MFMA16(mh) do { __builtin_amdgcn_s_setprio(1); _Pragma("unroll")      \
    for (int mm = 0; mm < 4; ++mm) { _Pragma("unroll")                        \
      for (int nn = 0; nn < 4; ++nn)                                          \
        acc[(mh) * 4 + mm][nn] = __builtin_amdgcn_mfma_f32_16x16x32_bf16(     \
            af[mm], bf[nn], acc[(mh) * 4 + mm][nn], 0, 0, 0); }               \
    __builtin_amdgcn_s_setprio(0); } while (0)

  f32x4 acc[8][4] = {};
  bf16x8 af[4], bf[4];

  // prologue: tile0 (B,A) + tile1 (B); vmcnt(2) allows tile1's B in flight
  STG_B(0, 0); STG_A(0, 0); STG_B(1, 1);
  VMC2(); BAR();

  for (int i = 0; i < ni; ++i) {
    const bool tail = (i == ni - 1);
    const int k2 = 2 * i;
    // ph1: tile k2 (par 0), m-half 0
    RD_AF(0, 0); RD_BF(0);
    STG_A(1, k2 + 1);
    BAR(); MFMA16(0); BAR();
    // ph2: m-half 1
    RD_AF(1, 0);
    if (!tail) { STG_B(0, k2 + 2); VMC2(); } else { VMC0(); }
    BAR(); MFMA16(1); BAR();
    // ph3: tile k2+1 (par 1), m-half 0
    RD_AF(0, 1); RD_BF(1);
    if (!tail) STG_A(0, k2 + 2);
    BAR(); MFMA16(0); BAR();
    // ph4: m-half 1
    RD_AF(1, 1);
    if (!tail) { STG_B(1, k2 + 3); VMC2(); }
    BAR(); MFMA16(1); BAR();
  }

  // direct-scatter epilogue (compile-time D divisions)
#pragma unroll
  for (int m = 0; m < 8; ++m)
#pragma unroll
    for (int j = 0; j < 4; ++j) {
      const int gr = m0 + wr * 128 + m * 16 + khi * 4 + j;
      const int bb = gr / D, ii = gr - bb * D;
      float* orow = out + (size_t)bb * 36608 + OFF + ii;
#pragma unroll
      for (int n = 0; n < 4; ++n) {
        const int gc = n0 + wc * 64 + n * 16 + r15;
        if (gc < NnM) {
          const int yo = gc / D, v = gc - yo * D;
          orow[yo * 286 + v * D] = acc[m][n][j];
        }
      }
    }
#undef STG_A
#undef STG_B
#undef RD_AF
#undef RD_BF
#undef MFMA16
}

__global__ __launch_bounds__(NT8, 2)
void main_gemm8(const __hip_bfloat16* __restrict__ Aall,
                const __hip_bfloat16* __restrict__ PTall,
                float* __restrict__ out) {
  __shared__ __hip_bfloat16 smem[8 * 4096];   // 64 KB: [par][A,B][half] x 8KB
  const int bx = blockIdx.x;
  if (bx < 132)      tile8<11, 165>(Aall, PTall, out, bx, smem);
  else if (bx < 222) tile8<9, 84>(Aall, PTall, out, bx - 132, smem);
  else if (bx < 278) tile8<7, 35>(Aall, PTall, out, bx - 222, smem);
  else if (bx < 308) tile8<5, 10>(Aall, PTall, out, bx - 278, smem);
  else if (bx < 320) tile8<3, 1>(Aall, PTall, out, bx - 308, smem);
  else               tile8<1, 0>(Aall, PTall, out, bx - 320, smem);
}

// ---------------------------------------------------------------------------
extern "C" void kernel_launch(void* const* d_in, const int* in_sizes, int n_in,
                              void* d_out, int out_size, void* d_ws, size_t ws_size,
                              hipStream_t stream) {
  const float* x  = (const float*)d_in[0];  // (512,128,286)
  const float* w  = (const float*)d_in[1];  // (128,128,512)
  const float* Dm = (const float*)d_in[2];  // (512,286)
  float* out = (float*)d_out;               // (512,128,286)

  // Workspace (bf16 elems): PT 16384*286 ; A 65536*286 ; wb 16384*512 ;
  // DT 384*512.
  __hip_bfloat16* PT = (__hip_bfloat16*)d_ws;
  __hip_bfloat16* A  = PT + 16384 * 286;
  __hip_bfloat16* wb = A + 65536 * 286;
  __hip_bfloat16* DT = wb + 16384 * 512;

  prep_all<<<dim3(7936), dim3(NT), 0, stream>>>(w, Dm, x, wb, DT, A);
  psi_mfma<<<dim3(128, 3), dim3(NT), 0, stream>>>(wb, DT, PT);
  main_gemm8<<<dim3(322), dim3(NT8), 0, stream>>>(A, PT, out);
}